// Round 10
// baseline (2029.267 us; speedup 1.0000x reference)
//
#include <hip/hip_runtime.h>
#include <type_traits>

// LSTM_69879117906487: T=256,B=256,I=1024,H=256,FC=128,C=8
// Round 10: k_lstm_8w v2 (all-builtin MFMA, R9 numerics).
//   + xg[t+1] register prefetch (hide per-step HBM miss)
//   + 16 W-frags PINNED in VGPRs via volatile "=v" loads (un-rematerializable)
//   + phase-interleaved streamed W loads (peak reg pressure under 256)
//   + raw s_barrier with lgkmcnt-only drain (skip vmcnt(0) store drain)
// Per wave (64 frags): VGPR-pinned 16 (kb0,1) + LDS 17 (kb2,3 + kb4/ti0)
//                      + stream 31 (kb4 ti1-7, kb5, kb6, kb7).

typedef float    f4    __attribute__((ext_vector_type(4)));
typedef float    f32x4 __attribute__((ext_vector_type(4)));
typedef _Float16 h8    __attribute__((ext_vector_type(8)));
typedef _Float16 h4    __attribute__((ext_vector_type(4)));

__device__ __forceinline__ float ldf(const float* p)    { return *p; }
__device__ __forceinline__ float ldf(const _Float16* p) { return (float)*p; }

__device__ __forceinline__ float fast_sigmoid(float x) {
    return 1.f / (1.f + __expf(-x));
}
__device__ __forceinline__ float fast_tanh(float x) {
    const float e = __expf(-2.f * fabsf(x));
    const float t = (1.f - e) / (1.f + e);
    return copysignf(t, x);
}

// Volatile load into VGPRs: the def cannot be rematerialized or deleted, so
// the value MUST stay register-resident across the loop. Consumed only by
// BUILTIN MFMAs (no asm MFMA -- that path corrupted R7/R8).
__device__ __forceinline__ f32x4 ld_pin(const _Float16* p) {
    f32x4 d;
    asm volatile("global_load_dwordx4 %0, %1, off\n\t"
                 "s_waitcnt vmcnt(0)"
                 : "=v"(d) : "v"(p) : "memory");
    return d;
}

// ---------------------------------------------------------------- bias
__global__ __launch_bounds__(256) void k_bias(const float* __restrict__ b_ih,
                                              const float* __restrict__ b_hh,
                                              float* __restrict__ bias) {
    const int i = blockIdx.x * 256 + threadIdx.x;
    if (i < 1024) bias[i] = b_ih[i] + b_hh[i];
}

// ---------------------------------------------------------------- W_hh pack
// fi = gt*8 + kb. Lane l elem j: W_hh[gt*16 + (l&15)][kb*32 + (l>>4)*8 + j].
__global__ __launch_bounds__(256) void k_pack(const float* __restrict__ W_hh,
                                              _Float16* __restrict__ Wp) {
    const int idx = blockIdx.x * 256 + threadIdx.x;
    const int fi = idx >> 6;
    const int l  = idx & 63;
    const int g  = (fi >> 3) * 16 + (l & 15);
    const int k  = (fi & 7) * 32 + ((l >> 4) << 3);
    const float* src = &W_hh[(size_t)g * 256 + k];
    h8 v;
    #pragma unroll
    for (int c = 0; c < 8; ++c) v[c] = (_Float16)src[c];
    *(h8*)&Wp[(size_t)idx * 8] = v;
}

// ---------------------------------------------------------------- xg GEMM (MFMA)
// 128x128 tile, BK=32, 256 thr. Epilogue -> 64 B/lane packets:
// base = (((t*16+g)*8 + w8)*64 + lane)*32, elem = gate*8 + jt*4 + r.
__global__ __launch_bounds__(256) void k_xg_mfma(
    const float* __restrict__ x, const float* __restrict__ W_ih,
    const float* __restrict__ bias, _Float16* __restrict__ xg2)
{
    __shared__ _Float16 As[2][128][40];
    __shared__ _Float16 Bs[2][128][40];
    const int tid = threadIdx.x;
    const int l   = tid & 63;
    const int w   = tid >> 6;
    const int m0  = blockIdx.y * 128;
    const int n0  = blockIdx.x * 128;
    const int wr  = (w >> 1) * 64;
    const int wc  = (w & 1) * 64;
    const int srow = tid >> 2;
    const int skof = (tid & 3) * 8;
    const int lr = l & 15;
    const int lg = l >> 4;

    f32x4 acc[4][4] = {};
    f4 ldA[2][2], ldB[2][2];

    auto XG_LOAD = [&](int kt) {
        const int k0 = kt * 32;
        #pragma unroll
        for (int s = 0; s < 2; ++s) {
            const float* xa = &x[(size_t)(m0 + srow + s * 64) * 1024 + k0 + skof];
            const float* wb = &W_ih[(size_t)(n0 + srow + s * 64) * 1024 + k0 + skof];
            ldA[s][0] = *(const f4*)xa; ldA[s][1] = *(const f4*)(xa + 4);
            ldB[s][0] = *(const f4*)wb; ldB[s][1] = *(const f4*)(wb + 4);
        }
    };
    auto XG_WRITE = [&](int buf) {
        #pragma unroll
        for (int s = 0; s < 2; ++s) {
            h8 va, vb;
            #pragma unroll
            for (int c = 0; c < 8; ++c) {
                va[c] = (_Float16)ldA[s][c >> 2][c & 3];
                vb[c] = (_Float16)ldB[s][c >> 2][c & 3];
            }
            *(h8*)&As[buf][srow + s * 64][skof] = va;
            *(h8*)&Bs[buf][srow + s * 64][skof] = vb;
        }
    };

    XG_LOAD(0);
    XG_WRITE(0);
    __syncthreads();
    for (int kt = 0; kt < 32; ++kt) {
        const int cur = kt & 1;
        if (kt + 1 < 32) XG_LOAD(kt + 1);
        h8 af[4], bf[4];
        #pragma unroll
        for (int mf = 0; mf < 4; ++mf) af[mf] = *(const h8*)&As[cur][wr + mf * 16 + lr][lg * 8];
        #pragma unroll
        for (int nf = 0; nf < 4; ++nf) bf[nf] = *(const h8*)&Bs[cur][wc + nf * 16 + lr][lg * 8];
        #pragma unroll
        for (int mf = 0; mf < 4; ++mf)
            #pragma unroll
            for (int nf = 0; nf < 4; ++nf)
                acc[mf][nf] = __builtin_amdgcn_mfma_f32_16x16x32_f16(af[mf], bf[nf], acc[mf][nf], 0, 0, 0);
        if (kt + 1 < 32) XG_WRITE((kt + 1) & 1);
        __syncthreads();
    }
    #pragma unroll
    for (int nf = 0; nf < 4; ++nf) {
        const int col  = n0 + wc + nf * 16 + lr;
        const float bv = bias[col];
        const int gate = col >> 8;
        const int w8   = (col >> 5) & 7;
        const int jt   = (col >> 4) & 1;
        #pragma unroll
        for (int mf = 0; mf < 4; ++mf) {
            const int rowb = m0 + wr + mf * 16 + lg * 4;
            const int tt = rowb >> 8;
            const int gb = (rowb >> 4) & 15;
            h4 pk;
            #pragma unroll
            for (int r = 0; r < 4; ++r) pk[r] = (_Float16)(acc[mf][nf][r] + bv);
            *(h4*)&xg2[((((size_t)tt * 16 + gb) * 8 + w8) * 64 + l) * 32 + gate * 8 + jt * 4] = pk;
        }
    }
}

// ---------------------------------------------------------------- recurrence
// 16 blocks x 512 thr (8 waves, 2/SIMD). Wave w owns j in [w*32,(w+1)*32):
// 8 tiles ti = gate*2 + jt, 8 kb each -> 64 frags.
//   PINNED VGPR 16 : kb 0,1 (volatile "=v" loads, un-rematerializable)
//   LDS 17         : kb 2 -> ti, kb 3 -> 8+ti, kb 4/ti==0 -> 16
//   STREAM 31      : kb4 ti 1..7 / kb5 / kb6 / kb7 (phase-interleaved)
__global__ __launch_bounds__(512, 2) void k_lstm_8w(
    const _Float16* __restrict__ xg2, const _Float16* __restrict__ Wp,
    _Float16* __restrict__ h_all)
{
    __shared__ _Float16 wlds[8 * 17 * 512];   // 139,264 B
    __shared__ _Float16 h_sh[2][16][264];     //  16,896 B  (total 156,160)
    const int tid = threadIdx.x;
    const int w  = tid >> 6;       // 0..7
    const int l  = tid & 63;
    const int lr = l & 15;
    const int lg = l >> 4;
    const int g  = blockIdx.x;
    const int b0 = g * 16;

    auto fgid = [&](int ti, int kb) {   // ti = gate*2+jt -> gt = gate*16 + w*2 + jt
        return (((ti >> 1) * 16 + w * 2 + (ti & 1)) * 8 + kb);
    };
    auto ldfrag = [&](int ti, int kb) {
        return *(const h8*)&Wp[((size_t)fgid(ti, kb) * 64 + l) * 8];
    };

    // ---- 16 PINNED VGPR frags (kb 0,1)
    f32x4 wpin[16];
    #pragma unroll
    for (int kb = 0; kb < 2; ++kb)
        #pragma unroll
        for (int ti = 0; ti < 8; ++ti)
            wpin[kb * 8 + ti] = ld_pin(&Wp[((size_t)fgid(ti, kb) * 64 + l) * 8]);

    // ---- 17 LDS frags per wave
    #pragma unroll
    for (int ti = 0; ti < 8; ++ti)
        *(h8*)&wlds[((w * 17 + ti) * 64 + l) * 8] = ldfrag(ti, 2);
    #pragma unroll
    for (int ti = 0; ti < 8; ++ti)
        *(h8*)&wlds[((w * 17 + 8 + ti) * 64 + l) * 8] = ldfrag(ti, 3);
    *(h8*)&wlds[((w * 17 + 16) * 64 + l) * 8] = ldfrag(0, 4);

    // zero h_sh
    {
        _Float16* p = &h_sh[0][0][0];
        for (int i = tid; i < 2 * 16 * 264; i += 512) p[i] = (_Float16)0.f;
    }
    __syncthreads();

    float c[8];
    #pragma unroll
    for (int i = 0; i < 8; ++i) c[i] = 0.f;

    // prologue: xg[0] packet
    h8 xq[4];
    {
        const size_t E0 = (((size_t)g * 8 + w) * 64 + l) * 32;
        #pragma unroll
        for (int q = 0; q < 4; ++q) xq[q] = *(const h8*)&xg2[E0 + q * 8];
    }

    for (int t = 0; t < 256; ++t) {
        const int cur = t & 1;
        const int nxt = cur ^ 1;

        // acc init = xg (MFMA C-operand accumulates the matmul on top)
        f32x4 acc[8];
        #pragma unroll
        for (int ti = 0; ti < 8; ++ti) {
            #pragma unroll
            for (int r = 0; r < 4; ++r)
                acc[ti][r] = (float)xq[ti >> 1][(ti & 1) * 4 + r];
        }

        // prefetch next step's xg packet (hide HBM latency under this step)
        h8 xqn[4];
        if (t < 255) {
            const size_t En = ((((size_t)(t + 1) * 16 + g) * 8 + w) * 64 + l) * 32;
            #pragma unroll
            for (int q = 0; q < 4; ++q) xqn[q] = *(const h8*)&xg2[En + q * 8];
        }

        // phase A streamed loads: kb4 ti1-7 + kb5 (issued before MFMA block)
        unsigned sA = 0;
        asm volatile("" : "+v"(sA));
        h8 sv4[7], sv5[8];
        #pragma unroll
        for (int ti = 1; ti < 8; ++ti)
            sv4[ti - 1] = *(const h8*)&Wp[((size_t)fgid(ti, 4) * 64 + l) * 8 + sA];
        #pragma unroll
        for (int ti = 0; ti < 8; ++ti)
            sv5[ti] = *(const h8*)&Wp[((size_t)fgid(ti, 5) * 64 + l) * 8 + sA];

        // kb0, kb1: pinned VGPR frags
        {
            h8 av = *(const h8*)&h_sh[cur][lr][0 * 32 + lg * 8];
            #pragma unroll
            for (int ti = 0; ti < 8; ++ti)
                acc[ti] = __builtin_amdgcn_mfma_f32_16x16x32_f16(av, __builtin_bit_cast(h8, wpin[ti]), acc[ti], 0, 0, 0);
            av = *(const h8*)&h_sh[cur][lr][1 * 32 + lg * 8];
            #pragma unroll
            for (int ti = 0; ti < 8; ++ti)
                acc[ti] = __builtin_amdgcn_mfma_f32_16x16x32_f16(av, __builtin_bit_cast(h8, wpin[8 + ti]), acc[ti], 0, 0, 0);
        }

        // phase B streamed loads: kb6
        unsigned sB = 0;
        asm volatile("" : "+v"(sB));
        h8 sv6[8];
        #pragma unroll
        for (int ti = 0; ti < 8; ++ti)
            sv6[ti] = *(const h8*)&Wp[((size_t)fgid(ti, 6) * 64 + l) * 8 + sB];

        // kb2, kb3: LDS frags
        {
            h8 av = *(const h8*)&h_sh[cur][lr][2 * 32 + lg * 8];
            #pragma unroll
            for (int ti = 0; ti < 8; ++ti) {
                const h8 b = *(const h8*)&wlds[((w * 17 + ti) * 64 + l) * 8];
                acc[ti] = __builtin_amdgcn_mfma_f32_16x16x32_f16(av, b, acc[ti], 0, 0, 0);
            }
            av = *(const h8*)&h_sh[cur][lr][3 * 32 + lg * 8];
            #pragma unroll
            for (int ti = 0; ti < 8; ++ti) {
                const h8 b = *(const h8*)&wlds[((w * 17 + 8 + ti) * 64 + l) * 8];
                acc[ti] = __builtin_amdgcn_mfma_f32_16x16x32_f16(av, b, acc[ti], 0, 0, 0);
            }
        }

        // kb4: ti0 from LDS, ti1-7 from sv4; kb5: sv5
        {
            h8 av = *(const h8*)&h_sh[cur][lr][4 * 32 + lg * 8];
            {
                const h8 b = *(const h8*)&wlds[((w * 17 + 16) * 64 + l) * 8];
                acc[0] = __builtin_amdgcn_mfma_f32_16x16x32_f16(av, b, acc[0], 0, 0, 0);
            }
            #pragma unroll
            for (int ti = 1; ti < 8; ++ti)
                acc[ti] = __builtin_amdgcn_mfma_f32_16x16x32_f16(av, sv4[ti - 1], acc[ti], 0, 0, 0);
            av = *(const h8*)&h_sh[cur][lr][5 * 32 + lg * 8];
            #pragma unroll
            for (int ti = 0; ti < 8; ++ti)
                acc[ti] = __builtin_amdgcn_mfma_f32_16x16x32_f16(av, sv5[ti], acc[ti], 0, 0, 0);
        }

        // phase C streamed loads: kb7 (after sv4/sv5 die -> pressure ok)
        unsigned sC = 0;
        asm volatile("" : "+v"(sC));
        h8 sv7[8];
        #pragma unroll
        for (int ti = 0; ti < 8; ++ti)
            sv7[ti] = *(const h8*)&Wp[((size_t)fgid(ti, 7) * 64 + l) * 8 + sC];

        // kb6, kb7
        {
            h8 av = *(const h8*)&h_sh[cur][lr][6 * 32 + lg * 8];
            #pragma unroll
            for (int ti = 0; ti < 8; ++ti)
                acc[ti] = __builtin_amdgcn_mfma_f32_16x16x32_f16(av, sv6[ti], acc[ti], 0, 0, 0);
            av = *(const h8*)&h_sh[cur][lr][7 * 32 + lg * 8];
            #pragma unroll
            for (int ti = 0; ti < 8; ++ti)
                acc[ti] = __builtin_amdgcn_mfma_f32_16x16x32_f16(av, sv7[ti], acc[ti], 0, 0, 0);
        }

        // activations: lane holds z for b = lg*4+r, j = w*32+jt*16+lr, all gates
        #pragma unroll
        for (int jt = 0; jt < 2; ++jt) {
            #pragma unroll
            for (int r = 0; r < 4; ++r) {
                const float ig = fast_sigmoid(acc[0 * 2 + jt][r]);
                const float fg = fast_sigmoid(acc[1 * 2 + jt][r]);
                const float gg = fast_tanh(acc[2 * 2 + jt][r]);
                const float og = fast_sigmoid(acc[3 * 2 + jt][r]);
                const int ci = jt * 4 + r;
                c[ci] = fg * c[ci] + ig * gg;
                const float hv = og * fast_tanh(c[ci]);
                const _Float16 h16 = (_Float16)hv;
                h_sh[nxt][lg * 4 + r][w * 32 + jt * 16 + lr] = h16;
                h_all[((size_t)t * 256 + b0 + lg * 4 + r) * 256 + w * 32 + jt * 16 + lr] = h16;
            }
        }

        // rotate xg prefetch
        if (t < 255) {
            #pragma unroll
            for (int q = 0; q < 4; ++q) xq[q] = xqn[q];
        }

        // raw barrier: drain LDS only (h_sh writes); global stores/loads keep
        // flowing across the barrier (vmcnt NOT drained -- the R9 stall).
        asm volatile("s_waitcnt lgkmcnt(0)" ::: "memory");
        __builtin_amdgcn_s_barrier();
        __builtin_amdgcn_sched_barrier(0);
    }
}

// ---------------------------------------------------------------- FC1+FC2
template <typename HT>
__global__ __launch_bounds__(256) void k_fc(
    const HT* __restrict__ h_all, const float* __restrict__ W1,
    const float* __restrict__ b1, const float* __restrict__ W2,
    const float* __restrict__ b2, float* __restrict__ out)
{
    __shared__ __align__(16) float smem[12288];
    float* hsT = smem;
    float* w1T = smem + 4096;
    const int tid = threadIdx.x;
    const int m0 = blockIdx.x * 64;
    const int tx = tid & 15;
    const int ty = tid >> 4;
    const int r0 = ty * 4;
    const int fA = tx * 4;
    const int fB = 64 + tx * 4;
    float acc[4][8] = {};
    for (int kc = 0; kc < 4; ++kc) {
        const int k0 = kc * 64;
        __syncthreads();
        #pragma unroll
        for (int i = 0; i < 4; ++i) {
            const int fid = tid + i * 256;
            const int rr = fid >> 4;
            const int qq = fid & 15;
            const HT* p = &h_all[(size_t)(m0 + rr) * 256 + k0 + qq * 4];
            f4 v;
            if constexpr (std::is_same<HT, float>::value) {
                v = *(const f4*)p;
            } else {
                v[0] = ldf(p); v[1] = ldf(p + 1); v[2] = ldf(p + 2); v[3] = ldf(p + 3);
            }
            #pragma unroll
            for (int cc = 0; cc < 4; ++cc)
                hsT[(qq * 4 + cc) * 64 + rr] = fmaxf(v[cc], 0.f);
        }
        #pragma unroll
        for (int i = 0; i < 8; ++i) {
            const int fid = tid + i * 256;
            const int ff = fid >> 4;
            const int qq = fid & 15;
            const f4 v = *(const f4*)&W1[(size_t)ff * 256 + k0 + qq * 4];
            #pragma unroll
            for (int cc = 0; cc < 4; ++cc)
                w1T[(qq * 4 + cc) * 128 + ff] = v[cc];
        }
        __syncthreads();
        #pragma unroll 4
        for (int kk = 0; kk < 64; ++kk) {
            const f4 aa = *(const f4*)&hsT[kk * 64 + r0];
            const f4 ba = *(const f4*)&w1T[kk * 128 + fA];
            const f4 bb = *(const f4*)&w1T[kk * 128 + fB];
            #pragma unroll
            for (int i = 0; i < 4; ++i) {
                #pragma unroll
                for (int j = 0; j < 4; ++j) {
                    acc[i][j]     = fmaf(aa[i], ba[j], acc[i][j]);
                    acc[i][j + 4] = fmaf(aa[i], bb[j], acc[i][j + 4]);
                }
            }
        }
    }
    __syncthreads();
    float* fc1s = smem;
    #pragma unroll
    for (int j = 0; j < 4; ++j) {
        const float bbA = b1[fA + j];
        const float bbB = b1[fB + j];
        #pragma unroll
        for (int i = 0; i < 4; ++i) {
            fc1s[(r0 + i) * 132 + fA + j] = fmaxf(acc[i][j] + bbA, 0.f);
            fc1s[(r0 + i) * 132 + fB + j] = fmaxf(acc[i][j + 4] + bbB, 0.f);
        }
    }
    __syncthreads();
    const int r  = tid >> 2;
    const int c0 = (tid & 3) * 2;
    float o0 = b2[c0], o1 = b2[c0 + 1];
    #pragma unroll
    for (int fq = 0; fq < 32; ++fq) {
        const f4 p  = *(const f4*)&fc1s[r * 132 + fq * 4];
        const f4 wa = *(const f4*)&W2[(size_t)c0 * 128 + fq * 4];
        const f4 wb = *(const f4*)&W2[(size_t)(c0 + 1) * 128 + fq * 4];
        o0 += p[0] * wa[0] + p[1] * wa[1] + p[2] * wa[2] + p[3] * wa[3];
        o1 += p[0] * wb[0] + p[1] * wb[1] + p[2] * wb[2] + p[3] * wb[3];
    }
    out[(size_t)(m0 + r) * 8 + c0]     = o0;
    out[(size_t)(m0 + r) * 8 + c0 + 1] = o1;
}

// ---------------------------------------------------------------- launch
extern "C" void kernel_launch(void* const* d_in, const int* in_sizes, int n_in,
                              void* d_out, int out_size, void* d_ws, size_t ws_size,
                              hipStream_t stream)
{
    const float* x    = (const float*)d_in[0];
    const float* W_ih = (const float*)d_in[1];
    const float* W_hh = (const float*)d_in[2];
    const float* b_ih = (const float*)d_in[3];
    const float* b_hh = (const float*)d_in[4];
    const float* W1   = (const float*)d_in[5];
    const float* b1   = (const float*)d_in[6];
    const float* W2   = (const float*)d_in[7];
    const float* b2   = (const float*)d_in[8];
    float* out = (float*)d_out;
    char* ws = (char*)d_ws;

    // workspace layout (168,300,544 B)
    _Float16* xg2   = (_Float16*)ws;                          // 134,217,728 B
    _Float16* h_all = (_Float16*)(ws + 134217728);            //  33,554,432 B
    _Float16* Wp    = (_Float16*)(ws + 167772160);            //     524,288 B
    float*    bias  = (float*)   (ws + 168296448);            //       4,096 B

    k_bias<<<4, 256, 0, stream>>>(b_ih, b_hh, bias);
    k_pack<<<128, 256, 0, stream>>>(W_hh, Wp);
    k_xg_mfma<<<dim3(8, 512), 256, 0, stream>>>(x, W_ih, bias, xg2);
    k_lstm_8w<<<16, 512, 0, stream>>>(xg2, Wp, h_all);
    k_fc<_Float16><<<1024, 256, 0, stream>>>(h_all, W1, b1, W2, b2, out);
}

// Round 11
// 2019.639 us; speedup vs baseline: 1.0048x; 1.0048x over previous
//
#include <hip/hip_runtime.h>
#include <type_traits>

// LSTM_69879117906487: T=256,B=256,I=1024,H=256,FC=128,C=8
// Round 11: R10 structure + amdgpu_waves_per_eu(2,2) on the recurrence.
// R9/R10 ran at VGPR_Count=128: launch_bounds(512,2) only sets MIN waves/EU,
// so the compiler targeted 4 waves/EU (128 regs) -- unreachable with 156 KB
// LDS -- and paid ~10x VALU in spill/remat (51% of active-CU cycles).
// waves_per_eu(2,2) fixes the budget at 256 VGPRs/lane.

typedef float    f4    __attribute__((ext_vector_type(4)));
typedef float    f32x4 __attribute__((ext_vector_type(4)));
typedef _Float16 h8    __attribute__((ext_vector_type(8)));
typedef _Float16 h4    __attribute__((ext_vector_type(4)));

__device__ __forceinline__ float ldf(const float* p)    { return *p; }
__device__ __forceinline__ float ldf(const _Float16* p) { return (float)*p; }

__device__ __forceinline__ float fast_sigmoid(float x) {
    return 1.f / (1.f + __expf(-x));
}
__device__ __forceinline__ float fast_tanh(float x) {
    const float e = __expf(-2.f * fabsf(x));
    const float t = (1.f - e) / (1.f + e);
    return copysignf(t, x);
}

// Volatile load into VGPRs: def cannot be rematerialized or deleted.
// Consumed only by BUILTIN MFMAs (asm MFMA corrupted R7/R8 -- never again).
__device__ __forceinline__ f32x4 ld_pin(const _Float16* p) {
    f32x4 d;
    asm volatile("global_load_dwordx4 %0, %1, off\n\t"
                 "s_waitcnt vmcnt(0)"
                 : "=v"(d) : "v"(p) : "memory");
    return d;
}

// ---------------------------------------------------------------- bias
__global__ __launch_bounds__(256) void k_bias(const float* __restrict__ b_ih,
                                              const float* __restrict__ b_hh,
                                              float* __restrict__ bias) {
    const int i = blockIdx.x * 256 + threadIdx.x;
    if (i < 1024) bias[i] = b_ih[i] + b_hh[i];
}

// ---------------------------------------------------------------- W_hh pack
// fi = gt*8 + kb. Lane l elem j: W_hh[gt*16 + (l&15)][kb*32 + (l>>4)*8 + j].
__global__ __launch_bounds__(256) void k_pack(const float* __restrict__ W_hh,
                                              _Float16* __restrict__ Wp) {
    const int idx = blockIdx.x * 256 + threadIdx.x;
    const int fi = idx >> 6;
    const int l  = idx & 63;
    const int g  = (fi >> 3) * 16 + (l & 15);
    const int k  = (fi & 7) * 32 + ((l >> 4) << 3);
    const float* src = &W_hh[(size_t)g * 256 + k];
    h8 v;
    #pragma unroll
    for (int c = 0; c < 8; ++c) v[c] = (_Float16)src[c];
    *(h8*)&Wp[(size_t)idx * 8] = v;
}

// ---------------------------------------------------------------- xg GEMM (MFMA)
// 128x128 tile, BK=32, 256 thr. Epilogue -> 64 B/lane packets:
// base = (((t*16+g)*8 + w8)*64 + lane)*32, elem = gate*8 + jt*4 + r.
__global__ __launch_bounds__(256) void k_xg_mfma(
    const float* __restrict__ x, const float* __restrict__ W_ih,
    const float* __restrict__ bias, _Float16* __restrict__ xg2)
{
    __shared__ _Float16 As[2][128][40];
    __shared__ _Float16 Bs[2][128][40];
    const int tid = threadIdx.x;
    const int l   = tid & 63;
    const int w   = tid >> 6;
    const int m0  = blockIdx.y * 128;
    const int n0  = blockIdx.x * 128;
    const int wr  = (w >> 1) * 64;
    const int wc  = (w & 1) * 64;
    const int srow = tid >> 2;
    const int skof = (tid & 3) * 8;
    const int lr = l & 15;
    const int lg = l >> 4;

    f32x4 acc[4][4] = {};
    f4 ldA[2][2], ldB[2][2];

    auto XG_LOAD = [&](int kt) {
        const int k0 = kt * 32;
        #pragma unroll
        for (int s = 0; s < 2; ++s) {
            const float* xa = &x[(size_t)(m0 + srow + s * 64) * 1024 + k0 + skof];
            const float* wb = &W_ih[(size_t)(n0 + srow + s * 64) * 1024 + k0 + skof];
            ldA[s][0] = *(const f4*)xa; ldA[s][1] = *(const f4*)(xa + 4);
            ldB[s][0] = *(const f4*)wb; ldB[s][1] = *(const f4*)(wb + 4);
        }
    };
    auto XG_WRITE = [&](int buf) {
        #pragma unroll
        for (int s = 0; s < 2; ++s) {
            h8 va, vb;
            #pragma unroll
            for (int c = 0; c < 8; ++c) {
                va[c] = (_Float16)ldA[s][c >> 2][c & 3];
                vb[c] = (_Float16)ldB[s][c >> 2][c & 3];
            }
            *(h8*)&As[buf][srow + s * 64][skof] = va;
            *(h8*)&Bs[buf][srow + s * 64][skof] = vb;
        }
    };

    XG_LOAD(0);
    XG_WRITE(0);
    __syncthreads();
    for (int kt = 0; kt < 32; ++kt) {
        const int cur = kt & 1;
        if (kt + 1 < 32) XG_LOAD(kt + 1);
        h8 af[4], bf[4];
        #pragma unroll
        for (int mf = 0; mf < 4; ++mf) af[mf] = *(const h8*)&As[cur][wr + mf * 16 + lr][lg * 8];
        #pragma unroll
        for (int nf = 0; nf < 4; ++nf) bf[nf] = *(const h8*)&Bs[cur][wc + nf * 16 + lr][lg * 8];
        #pragma unroll
        for (int mf = 0; mf < 4; ++mf)
            #pragma unroll
            for (int nf = 0; nf < 4; ++nf)
                acc[mf][nf] = __builtin_amdgcn_mfma_f32_16x16x32_f16(af[mf], bf[nf], acc[mf][nf], 0, 0, 0);
        if (kt + 1 < 32) XG_WRITE((kt + 1) & 1);
        __syncthreads();
    }
    #pragma unroll
    for (int nf = 0; nf < 4; ++nf) {
        const int col  = n0 + wc + nf * 16 + lr;
        const float bv = bias[col];
        const int gate = col >> 8;
        const int w8   = (col >> 5) & 7;
        const int jt   = (col >> 4) & 1;
        #pragma unroll
        for (int mf = 0; mf < 4; ++mf) {
            const int rowb = m0 + wr + mf * 16 + lg * 4;
            const int tt = rowb >> 8;
            const int gb = (rowb >> 4) & 15;
            h4 pk;
            #pragma unroll
            for (int r = 0; r < 4; ++r) pk[r] = (_Float16)(acc[mf][nf][r] + bv);
            *(h4*)&xg2[((((size_t)tt * 16 + gb) * 8 + w8) * 64 + l) * 32 + gate * 8 + jt * 4] = pk;
        }
    }
}

// ---------------------------------------------------------------- recurrence
// 16 blocks x 512 thr (8 waves, EXACTLY 2/SIMD -> 256 VGPR budget).
// Wave w owns j in [w*32,(w+1)*32): 8 tiles ti = gate*2 + jt, 8 kb each.
//   PINNED VGPR 16 : kb 0,1 (volatile "=v" loads)
//   LDS 17         : kb 2 -> ti, kb 3 -> 8+ti, kb 4/ti==0 -> 16
//   STREAM 31      : kb4 ti 1..7 / kb5 / kb6 / kb7 (phase-interleaved)
__global__
__attribute__((amdgpu_flat_work_group_size(512, 512), amdgpu_waves_per_eu(2, 2)))
void k_lstm_8w(
    const _Float16* __restrict__ xg2, const _Float16* __restrict__ Wp,
    _Float16* __restrict__ h_all)
{
    __shared__ _Float16 wlds[8 * 17 * 512];   // 139,264 B
    __shared__ _Float16 h_sh[2][16][264];     //  16,896 B  (total 156,160)
    const int tid = threadIdx.x;
    const int w  = tid >> 6;       // 0..7
    const int l  = tid & 63;
    const int lr = l & 15;
    const int lg = l >> 4;
    const int g  = blockIdx.x;
    const int b0 = g * 16;

    auto fgid = [&](int ti, int kb) {   // ti = gate*2+jt -> gt = gate*16 + w*2 + jt
        return (((ti >> 1) * 16 + w * 2 + (ti & 1)) * 8 + kb);
    };
    auto ldfrag = [&](int ti, int kb) {
        return *(const h8*)&Wp[((size_t)fgid(ti, kb) * 64 + l) * 8];
    };

    // ---- 16 PINNED VGPR frags (kb 0,1)
    f32x4 wpin[16];
    #pragma unroll
    for (int kb = 0; kb < 2; ++kb)
        #pragma unroll
        for (int ti = 0; ti < 8; ++ti)
            wpin[kb * 8 + ti] = ld_pin(&Wp[((size_t)fgid(ti, kb) * 64 + l) * 8]);

    // ---- 17 LDS frags per wave
    #pragma unroll
    for (int ti = 0; ti < 8; ++ti)
        *(h8*)&wlds[((w * 17 + ti) * 64 + l) * 8] = ldfrag(ti, 2);
    #pragma unroll
    for (int ti = 0; ti < 8; ++ti)
        *(h8*)&wlds[((w * 17 + 8 + ti) * 64 + l) * 8] = ldfrag(ti, 3);
    *(h8*)&wlds[((w * 17 + 16) * 64 + l) * 8] = ldfrag(0, 4);

    // zero h_sh
    {
        _Float16* p = &h_sh[0][0][0];
        for (int i = tid; i < 2 * 16 * 264; i += 512) p[i] = (_Float16)0.f;
    }
    __syncthreads();

    float c[8];
    #pragma unroll
    for (int i = 0; i < 8; ++i) c[i] = 0.f;

    // prologue: xg[0] packet
    h8 xq[4];
    {
        const size_t E0 = (((size_t)g * 8 + w) * 64 + l) * 32;
        #pragma unroll
        for (int q = 0; q < 4; ++q) xq[q] = *(const h8*)&xg2[E0 + q * 8];
    }

    for (int t = 0; t < 256; ++t) {
        const int cur = t & 1;
        const int nxt = cur ^ 1;

        // acc init = xg (MFMA C-operand accumulates the matmul on top)
        f32x4 acc[8];
        #pragma unroll
        for (int ti = 0; ti < 8; ++ti) {
            #pragma unroll
            for (int r = 0; r < 4; ++r)
                acc[ti][r] = (float)xq[ti >> 1][(ti & 1) * 4 + r];
        }

        // prefetch next step's xg packet (hide HBM/L3 latency under this step)
        h8 xqn[4];
        if (t < 255) {
            const size_t En = ((((size_t)(t + 1) * 16 + g) * 8 + w) * 64 + l) * 32;
            #pragma unroll
            for (int q = 0; q < 4; ++q) xqn[q] = *(const h8*)&xg2[En + q * 8];
        }

        // phase A streamed loads: kb4 ti1-7 + kb5 (issued before MFMA block)
        unsigned sA = 0;
        asm volatile("" : "+v"(sA));
        h8 sv4[7], sv5[8];
        #pragma unroll
        for (int ti = 1; ti < 8; ++ti)
            sv4[ti - 1] = *(const h8*)&Wp[((size_t)fgid(ti, 4) * 64 + l) * 8 + sA];
        #pragma unroll
        for (int ti = 0; ti < 8; ++ti)
            sv5[ti] = *(const h8*)&Wp[((size_t)fgid(ti, 5) * 64 + l) * 8 + sA];

        // kb0, kb1: pinned VGPR frags
        {
            h8 av = *(const h8*)&h_sh[cur][lr][0 * 32 + lg * 8];
            #pragma unroll
            for (int ti = 0; ti < 8; ++ti)
                acc[ti] = __builtin_amdgcn_mfma_f32_16x16x32_f16(av, __builtin_bit_cast(h8, wpin[ti]), acc[ti], 0, 0, 0);
            av = *(const h8*)&h_sh[cur][lr][1 * 32 + lg * 8];
            #pragma unroll
            for (int ti = 0; ti < 8; ++ti)
                acc[ti] = __builtin_amdgcn_mfma_f32_16x16x32_f16(av, __builtin_bit_cast(h8, wpin[8 + ti]), acc[ti], 0, 0, 0);
        }

        // phase B streamed loads: kb6
        unsigned sB = 0;
        asm volatile("" : "+v"(sB));
        h8 sv6[8];
        #pragma unroll
        for (int ti = 0; ti < 8; ++ti)
            sv6[ti] = *(const h8*)&Wp[((size_t)fgid(ti, 6) * 64 + l) * 8 + sB];

        // kb2, kb3: LDS frags
        {
            h8 av = *(const h8*)&h_sh[cur][lr][2 * 32 + lg * 8];
            #pragma unroll
            for (int ti = 0; ti < 8; ++ti) {
                const h8 b = *(const h8*)&wlds[((w * 17 + ti) * 64 + l) * 8];
                acc[ti] = __builtin_amdgcn_mfma_f32_16x16x32_f16(av, b, acc[ti], 0, 0, 0);
            }
            av = *(const h8*)&h_sh[cur][lr][3 * 32 + lg * 8];
            #pragma unroll
            for (int ti = 0; ti < 8; ++ti) {
                const h8 b = *(const h8*)&wlds[((w * 17 + 8 + ti) * 64 + l) * 8];
                acc[ti] = __builtin_amdgcn_mfma_f32_16x16x32_f16(av, b, acc[ti], 0, 0, 0);
            }
        }

        // kb4: ti0 from LDS, ti1-7 from sv4; kb5: sv5
        {
            h8 av = *(const h8*)&h_sh[cur][lr][4 * 32 + lg * 8];
            {
                const h8 b = *(const h8*)&wlds[((w * 17 + 16) * 64 + l) * 8];
                acc[0] = __builtin_amdgcn_mfma_f32_16x16x32_f16(av, b, acc[0], 0, 0, 0);
            }
            #pragma unroll
            for (int ti = 1; ti < 8; ++ti)
                acc[ti] = __builtin_amdgcn_mfma_f32_16x16x32_f16(av, sv4[ti - 1], acc[ti], 0, 0, 0);
            av = *(const h8*)&h_sh[cur][lr][5 * 32 + lg * 8];
            #pragma unroll
            for (int ti = 0; ti < 8; ++ti)
                acc[ti] = __builtin_amdgcn_mfma_f32_16x16x32_f16(av, sv5[ti], acc[ti], 0, 0, 0);
        }

        // phase C streamed loads: kb7 (after sv4/sv5 die -> pressure ok)
        unsigned sC = 0;
        asm volatile("" : "+v"(sC));
        h8 sv7[8];
        #pragma unroll
        for (int ti = 0; ti < 8; ++ti)
            sv7[ti] = *(const h8*)&Wp[((size_t)fgid(ti, 7) * 64 + l) * 8 + sC];

        // kb6, kb7
        {
            h8 av = *(const h8*)&h_sh[cur][lr][6 * 32 + lg * 8];
            #pragma unroll
            for (int ti = 0; ti < 8; ++ti)
                acc[ti] = __builtin_amdgcn_mfma_f32_16x16x32_f16(av, sv6[ti], acc[ti], 0, 0, 0);
            av = *(const h8*)&h_sh[cur][lr][7 * 32 + lg * 8];
            #pragma unroll
            for (int ti = 0; ti < 8; ++ti)
                acc[ti] = __builtin_amdgcn_mfma_f32_16x16x32_f16(av, sv7[ti], acc[ti], 0, 0, 0);
        }

        // activations: lane holds z for b = lg*4+r, j = w*32+jt*16+lr, all gates
        #pragma unroll
        for (int jt = 0; jt < 2; ++jt) {
            #pragma unroll
            for (int r = 0; r < 4; ++r) {
                const float ig = fast_sigmoid(acc[0 * 2 + jt][r]);
                const float fg = fast_sigmoid(acc[1 * 2 + jt][r]);
                const float gg = fast_tanh(acc[2 * 2 + jt][r]);
                const float og = fast_sigmoid(acc[3 * 2 + jt][r]);
                const int ci = jt * 4 + r;
                c[ci] = fg * c[ci] + ig * gg;
                const float hv = og * fast_tanh(c[ci]);
                const _Float16 h16 = (_Float16)hv;
                h_sh[nxt][lg * 4 + r][w * 32 + jt * 16 + lr] = h16;
                h_all[((size_t)t * 256 + b0 + lg * 4 + r) * 256 + w * 32 + jt * 16 + lr] = h16;
            }
        }

        // rotate xg prefetch
        if (t < 255) {
            #pragma unroll
            for (int q = 0; q < 4; ++q) xq[q] = xqn[q];
        }

        // raw barrier: drain LDS only (h_sh writes); global stores/loads keep
        // flowing across the barrier.
        asm volatile("s_waitcnt lgkmcnt(0)" ::: "memory");
        __builtin_amdgcn_s_barrier();
        __builtin_amdgcn_sched_barrier(0);
    }
}

// ---------------------------------------------------------------- FC1+FC2
template <typename HT>
__global__ __launch_bounds__(256) void k_fc(
    const HT* __restrict__ h_all, const float* __restrict__ W1,
    const float* __restrict__ b1, const float* __restrict__ W2,
    const float* __restrict__ b2, float* __restrict__ out)
{
    __shared__ __align__(16) float smem[12288];
    float* hsT = smem;
    float* w1T = smem + 4096;
    const int tid = threadIdx.x;
    const int m0 = blockIdx.x * 64;
    const int tx = tid & 15;
    const int ty = tid >> 4;
    const int r0 = ty * 4;
    const int fA = tx * 4;
    const int fB = 64 + tx * 4;
    float acc[4][8] = {};
    for (int kc = 0; kc < 4; ++kc) {
        const int k0 = kc * 64;
        __syncthreads();
        #pragma unroll
        for (int i = 0; i < 4; ++i) {
            const int fid = tid + i * 256;
            const int rr = fid >> 4;
            const int qq = fid & 15;
            const HT* p = &h_all[(size_t)(m0 + rr) * 256 + k0 + qq * 4];
            f4 v;
            if constexpr (std::is_same<HT, float>::value) {
                v = *(const f4*)p;
            } else {
                v[0] = ldf(p); v[1] = ldf(p + 1); v[2] = ldf(p + 2); v[3] = ldf(p + 3);
            }
            #pragma unroll
            for (int cc = 0; cc < 4; ++cc)
                hsT[(qq * 4 + cc) * 64 + rr] = fmaxf(v[cc], 0.f);
        }
        #pragma unroll
        for (int i = 0; i < 8; ++i) {
            const int fid = tid + i * 256;
            const int ff = fid >> 4;
            const int qq = fid & 15;
            const f4 v = *(const f4*)&W1[(size_t)ff * 256 + k0 + qq * 4];
            #pragma unroll
            for (int cc = 0; cc < 4; ++cc)
                w1T[(qq * 4 + cc) * 128 + ff] = v[cc];
        }
        __syncthreads();
        #pragma unroll 4
        for (int kk = 0; kk < 64; ++kk) {
            const f4 aa = *(const f4*)&hsT[kk * 64 + r0];
            const f4 ba = *(const f4*)&w1T[kk * 128 + fA];
            const f4 bb = *(const f4*)&w1T[kk * 128 + fB];
            #pragma unroll
            for (int i = 0; i < 4; ++i) {
                #pragma unroll
                for (int j = 0; j < 4; ++j) {
                    acc[i][j]     = fmaf(aa[i], ba[j], acc[i][j]);
                    acc[i][j + 4] = fmaf(aa[i], bb[j], acc[i][j + 4]);
                }
            }
        }
    }
    __syncthreads();
    float* fc1s = smem;
    #pragma unroll
    for (int j = 0; j < 4; ++j) {
        const float bbA = b1[fA + j];
        const float bbB = b1[fB + j];
        #pragma unroll
        for (int i = 0; i < 4; ++i) {
            fc1s[(r0 + i) * 132 + fA + j] = fmaxf(acc[i][j] + bbA, 0.f);
            fc1s[(r0 + i) * 132 + fB + j] = fmaxf(acc[i][j + 4] + bbB, 0.f);
        }
    }
    __syncthreads();
    const int r  = tid >> 2;
    const int c0 = (tid & 3) * 2;
    float o0 = b2[c0], o1 = b2[c0 + 1];
    #pragma unroll
    for (int fq = 0; fq < 32; ++fq) {
        const f4 p  = *(const f4*)&fc1s[r * 132 + fq * 4];
        const f4 wa = *(const f4*)&W2[(size_t)c0 * 128 + fq * 4];
        const f4 wb = *(const f4*)&W2[(size_t)(c0 + 1) * 128 + fq * 4];
        o0 += p[0] * wa[0] + p[1] * wa[1] + p[2] * wa[2] + p[3] * wa[3];
        o1 += p[0] * wb[0] + p[1] * wb[1] + p[2] * wb[2] + p[3] * wb[3];
    }
    out[(size_t)(m0 + r) * 8 + c0]     = o0;
    out[(size_t)(m0 + r) * 8 + c0 + 1] = o1;
}

// ---------------------------------------------------------------- launch
extern "C" void kernel_launch(void* const* d_in, const int* in_sizes, int n_in,
                              void* d_out, int out_size, void* d_ws, size_t ws_size,
                              hipStream_t stream)
{
    const float* x    = (const float*)d_in[0];
    const float* W_ih = (const float*)d_in[1];
    const float* W_hh = (const float*)d_in[2];
    const float* b_ih = (const float*)d_in[3];
    const float* b_hh = (const float*)d_in[4];
    const float* W1   = (const float*)d_in[5];
    const float* b1   = (const float*)d_in[6];
    const float* W2   = (const float*)d_in[7];
    const float* b2   = (const float*)d_in[8];
    float* out = (float*)d_out;
    char* ws = (char*)d_ws;

    // workspace layout (168,300,544 B)
    _Float16* xg2   = (_Float16*)ws;                          // 134,217,728 B
    _Float16* h_all = (_Float16*)(ws + 134217728);            //  33,554,432 B
    _Float16* Wp    = (_Float16*)(ws + 167772160);            //     524,288 B
    float*    bias  = (float*)   (ws + 168296448);            //       4,096 B

    k_bias<<<4, 256, 0, stream>>>(b_ih, b_hh, bias);
    k_pack<<<128, 256, 0, stream>>>(W_hh, Wp);
    k_xg_mfma<<<dim3(8, 512), 256, 0, stream>>>(x, W_ih, bias, xg2);
    k_lstm_8w<<<16, 512, 0, stream>>>(xg2, Wp, h_all);
    k_fc<_Float16><<<1024, 256, 0, stream>>>(h_all, W1, b1, W2, b2, out);
}